// Round 6
// baseline (212.912 us; speedup 1.0000x reference)
//
#include <hip/hip_runtime.h>
#include <math.h>

#define BB 4
#define LL 512
#define DD 256
#define HH 8
#define DHH 32
#define NB 12  // BUCKETS + 1 (row 11 is the zero padding row)

// Kernel 1: Q,K,V projections, one matrix per block. Block = (mat, 8 rows).
// mat 2 (V) is written TRANSPOSED: VT[b][d][k] (k contiguous) for ctx_out streaming.
__global__ __launch_bounds__(256) void qkv_kernel(const float* __restrict__ x,
    const float* __restrict__ Wq, const float* __restrict__ bq,
    const float* __restrict__ Wk, const float* __restrict__ bk,
    const float* __restrict__ Wv, const float* __restrict__ bv,
    float* __restrict__ Q, float* __restrict__ K, float* __restrict__ VT) {
    __shared__ float xs[8][DD];
    const int mat = blockIdx.x >> 8;          // 0=Q, 1=K, 2=V (256 row-tiles each)
    const int r0 = (blockIdx.x & 255) * 8;
    const int c = threadIdx.x;
    const float* W;
    const float* bias;
    if (mat == 0)      { W = Wq; bias = bq; }
    else if (mat == 1) { W = Wk; bias = bk; }
    else               { W = Wv; bias = bv; }
    {   // stage 8 contiguous rows of x via float4
        float4* xsv = (float4*)&xs[0][0];                 // 512 float4
        const float4* xg = (const float4*)&x[r0 * DD];
        xsv[c] = xg[c];
        xsv[c + 256] = xg[c + 256];
    }
    __syncthreads();
    float acc[8];
#pragma unroll
    for (int r = 0; r < 8; ++r) acc[r] = bias[c];
    for (int i = 0; i < DD; ++i) {
        const float wv = W[i * DD + c];
#pragma unroll
        for (int r = 0; r < 8; ++r) acc[r] = fmaf(xs[r][i], wv, acc[r]);
    }
    if (mat == 0) {
#pragma unroll
        for (int r = 0; r < 8; ++r)
            Q[(r0 + r) * DD + c] = acc[r] * 0.17677669529663687f;  // 1/sqrt(DH)
    } else if (mat == 1) {
#pragma unroll
        for (int r = 0; r < 8; ++r) K[(r0 + r) * DD + c] = acc[r];
    } else {
        const int b = r0 >> 9;        // 8-row tiles never straddle a batch boundary
        const int lk = r0 & 511;
        float* vtp = VT + ((long)(b * DD + c)) * LL + lk;
#pragma unroll
        for (int r = 0; r < 8; ++r) vtp[r] = acc[r];
    }
}

// Kernel 2: fused rel-P + scores + softmax. Block = (b, 8-q tile, h), 512 threads.
// Thread t owns column k=t for 8 q rows. No max-subtraction (scores bounded ~±1;
// masked lanes e=0 exactly). Deterministic: all LDS handoffs write-all->barrier->read.
__global__ __launch_bounds__(512) void scores_kernel(const float* __restrict__ Q,
    const float* __restrict__ Km, const float* __restrict__ uvec,
    const float* __restrict__ vvec, const float* __restrict__ rel_table,
    const int* __restrict__ mask, const int* __restrict__ dist,
    float* __restrict__ attn) {
    __shared__ float Qu[8][DHH];        // q + u
    __shared__ float Qv8[8][DHH];       // q + v
    __shared__ float rels[NB][DHH + 1]; // head slice of rel_table, padded
    __shared__ float Ps[8][NB];
    __shared__ float wsum[8][8];        // [row][wave]
    const int blk = blockIdx.x;         // ((b*64 + qt)*8 + h)
    const int h = blk & 7;
    const int rest = blk >> 3;
    const int qt = rest & 63;
    const int b = rest >> 6;
    const int q0 = qt * 8;
    const int t = threadIdx.x;          // k index 0..511
    const int w = t >> 6, l = t & 63;

    if (t < 256) {                      // stage Q(+u) and Q(+v): 8 rows x 32 cols
        const int r = t >> 5, c = t & 31;
        const float qv = Q[(b * LL + q0 + r) * DD + h * DHH + c];
        Qu[r][c]  = qv + uvec[h * DHH + c];
        Qv8[r][c] = qv + vvec[h * DHH + c];
    }
    if (t < NB * DHH) {                 // stage rel_table head slice: 12 x 32
        rels[t >> 5][t & 31] = rel_table[(t >> 5) * DD + h * DHH + (t & 31)];
    }
    __syncthreads();
    if (t < 8 * NB) {                   // P[r][bk] = dot32(Qv8[r], rels[bk])
        const int bk = t >> 3, r = t & 7;
        float a = 0.f;
#pragma unroll
        for (int d = 0; d < DHH; ++d) a = fmaf(Qv8[r][d], rels[bk][d], a);
        Ps[r][bk] = a;
    }
    __syncthreads();

    float4 kr[8];
    const float4* kp = (const float4*)&Km[(b * LL + t) * DD + h * DHH];
#pragma unroll
    for (int j = 0; j < 8; ++j) kr[j] = kp[j];

    int dv[8], mv[8];                   // hoist: 16 independent loads in flight
#pragma unroll
    for (int r = 0; r < 8; ++r) {
        const int mq = (b * LL + q0 + r) * LL + t;
        dv[r] = dist[mq];
        mv[r] = mask[mq];
    }

    float e[8];
#pragma unroll
    for (int r = 0; r < 8; ++r) {
        float acc = Ps[r][dv[r]];
        const float4* qup = (const float4*)&Qu[r][0];   // ds_read_b128 x8
#pragma unroll
        for (int j = 0; j < 8; ++j) {
            const float4 qq = qup[j];
            acc = fmaf(qq.x, kr[j].x, acc);
            acc = fmaf(qq.y, kr[j].y, acc);
            acc = fmaf(qq.z, kr[j].z, acc);
            acc = fmaf(qq.w, kr[j].w, acc);
        }
        e[r] = mv[r] ? 0.f : __expf(acc);
    }

    float sm[8];
#pragma unroll
    for (int r = 0; r < 8; ++r) {
        float s = e[r];
        for (int off = 32; off > 0; off >>= 1) s += __shfl_xor(s, off);
        sm[r] = s;
    }
    if (l == 0) {
#pragma unroll
        for (int r = 0; r < 8; ++r) wsum[r][w] = sm[r];
    }
    __syncthreads();
#pragma unroll
    for (int r = 0; r < 8; ++r) {
        float tot = wsum[r][0];
#pragma unroll
        for (int i = 1; i < 8; ++i) tot += wsum[r][i];
        attn[((long)(b * HH + h) * LL + q0 + r) * LL + t] = e[r] * (1.0f / tot);
    }
}

// Kernel 3: fused ctx + output projection. Block = (b, 4 q rows), thread = d.
// VT gives per-thread contiguous float4 k-streams; k-step 8 with split accumulators.
__global__ __launch_bounds__(256) void ctx_out_kernel(const float* __restrict__ attn,
    const float* __restrict__ VT, const float* __restrict__ Wo,
    const float* __restrict__ bo, float* __restrict__ out) {
    __shared__ float Cs[4][DD];
    const int blk = blockIdx.x;          // b*128 + qt
    const int b = blk >> 7;
    const int q0 = (blk & 127) * 4;
    const int d = threadIdx.x;
    const int h = d >> 5;
    const float* vt = VT + ((long)(b * DD + d)) * LL;     // contiguous in k
    const float* ab = attn + ((long)(b * HH + h) * LL + q0) * LL;
    float accA[4] = {0.f, 0.f, 0.f, 0.f};
    float accB[4] = {0.f, 0.f, 0.f, 0.f};
    for (int k0 = 0; k0 < LL; k0 += 8) {
        const float4 v0 = *(const float4*)&vt[k0];
        const float4 v1 = *(const float4*)&vt[k0 + 4];
#pragma unroll
        for (int q = 0; q < 4; ++q) {
            const float4 a0 = *(const float4*)&ab[q * LL + k0];     // broadcast in head
            const float4 a1 = *(const float4*)&ab[q * LL + k0 + 4];
            accA[q] = fmaf(a0.x, v0.x, fmaf(a0.y, v0.y, fmaf(a0.z, v0.z, fmaf(a0.w, v0.w, accA[q]))));
            accB[q] = fmaf(a1.x, v1.x, fmaf(a1.y, v1.y, fmaf(a1.z, v1.z, fmaf(a1.w, v1.w, accB[q]))));
        }
    }
#pragma unroll
    for (int q = 0; q < 4; ++q) Cs[q][d] = accA[q] + accB[q];
    __syncthreads();
    float o[4];
#pragma unroll
    for (int q = 0; q < 4; ++q) o[q] = bo[d];
    for (int i = 0; i < DD; i += 4) {
        const float w0 = Wo[(i + 0) * DD + d];
        const float w1 = Wo[(i + 1) * DD + d];
        const float w2 = Wo[(i + 2) * DD + d];
        const float w3 = Wo[(i + 3) * DD + d];
#pragma unroll
        for (int q = 0; q < 4; ++q) {
            const float4 cv = *(const float4*)&Cs[q][i];
            o[q] = fmaf(cv.x, w0, fmaf(cv.y, w1, fmaf(cv.z, w2, fmaf(cv.w, w3, o[q]))));
        }
    }
#pragma unroll
    for (int q = 0; q < 4; ++q) out[(b * LL + q0 + q) * DD + d] = o[q];
}

extern "C" void kernel_launch(void* const* d_in, const int* in_sizes, int n_in,
                              void* d_out, int out_size, void* d_ws, size_t ws_size,
                              hipStream_t stream) {
    const float* x    = (const float*)d_in[0];
    const int* mk     = (const int*)d_in[1];   // jax bool -> int32
    const int* dist   = (const int*)d_in[2];
    const float* Wq = (const float*)d_in[3];
    const float* bq = (const float*)d_in[4];
    const float* Wk = (const float*)d_in[5];
    const float* bk = (const float*)d_in[6];
    const float* Wv = (const float*)d_in[7];
    const float* bv = (const float*)d_in[8];
    const float* Wo = (const float*)d_in[9];
    const float* bo = (const float*)d_in[10];
    const float* rel_table = (const float*)d_in[11];
    const float* uvec = (const float*)d_in[12];
    const float* vvec = (const float*)d_in[13];

    float* out  = (float*)d_out;                 // (B,L,D)
    float* attn = out + BB * LL * DD;            // (B,H,L,L)

    float* Q  = (float*)d_ws;
    float* K  = Q + BB * LL * DD;
    float* VT = K + BB * LL * DD;                // transposed V: [B][D][L], 6 MB ws total

    qkv_kernel<<<3 * 256, 256, 0, stream>>>(x, Wq, bq, Wk, bk, Wv, bv, Q, K, VT);
    scores_kernel<<<BB * (LL / 8) * HH, 512, 0, stream>>>(Q, K, uvec, vvec, rel_table,
                                                          mk, dist, attn);
    ctx_out_kernel<<<BB * (LL / 4), 256, 0, stream>>>(attn, VT, Wo, bo, out);
}